// Round 8
// baseline (41.437 us; speedup 1.0000x reference)
//
#include <hip/hip_runtime.h>

typedef float v4f __attribute__((ext_vector_type(4)));

#define NATOM 128
#define FEAT 128
#define FILT 128
#define BATCH 8

// Kernel 1 (unchanged from R7): s-GEMM, 2 rows per block, 512 blocks.
__global__ __launch_bounds__(256) void s_gemm_kernel(
    const float* __restrict__ sf, const float* __restrict__ W,
    const float* __restrict__ bias, float* __restrict__ s1,
    float* __restrict__ s2) {
  const int r0 = blockIdx.x * 2;
  const int tid = threadIdx.x;
  const int k = tid & (FILT - 1);
  const int which = tid >> 7;  // 0 -> s1, 1 -> s2

  __shared__ float sfrow[2][FEAT];
  sfrow[tid >> 7][tid & 127] = sf[(r0 + (tid >> 7)) * FEAT + (tid & 127)];
  __syncthreads();

  const float* Wcol = W + which * FEAT * FILT + k;
  float a0 = 0.f, a1 = 0.f;
#pragma unroll 4
  for (int f4 = 0; f4 < FEAT; f4 += 4) {
    const v4f sv0 = *reinterpret_cast<const v4f*>(&sfrow[0][f4]);
    const v4f sv1 = *reinterpret_cast<const v4f*>(&sfrow[1][f4]);
#pragma unroll
    for (int fi = 0; fi < 4; ++fi) {
      const float w = Wcol[(f4 + fi) * FILT];
      a0 = fmaf(sv0[fi], w, a0);
      a1 = fmaf(sv1[fi], w, a1);
    }
  }

  const float bb = which ? 0.f : bias[k];
  float* dst = (which ? s2 : s1) + r0 * FILT + k;
  dst[0] = a0 + bb;
  dst[FILT] = a1 + bb;
}

// Kernel 2: out[b,i,j,c,k] = (s1[b,i,k] + s2[b,j,k]) * dist[b,i,j,c]
// 2048 blocks (b,i,j-half), 4 waves/block. R7->R8 change: each wave handles
// j-PAIRS; the 3 KB pair-region (2j x 3c x 128k) is written as 3 fully
// CONTIGUOUS lane-linear 1 KB float4 stores (vs 6 stores of 2x512B split
// segments). Both half-waves hold the same k-quad; (p, d) selected by
// half-wave-uniform cndmask. Fill kernel writes contiguous 1KB/instr at
// 6.9 TB/s — this matches that store shape.
__global__ __launch_bounds__(256) void expand_kernel(
    const float* __restrict__ s1, const float* __restrict__ s2,
    const float* __restrict__ dist, float* __restrict__ out) {
  const int blk = blockIdx.x;
  const int bi = blk >> 1;          // b*N + i
  const int jh = blk & 1;           // j half
  const int b = bi >> 7;
  const int tid = threadIdx.x;
  const int lane = tid & 63;
  const int w = tid >> 6;           // wave 0..3
  const int hl = lane >> 5;         // half-wave 0/1
  const int kq = (lane & 31) << 2;  // k: 0..124 step 4 (both half-waves)

  const v4f s1v = *reinterpret_cast<const v4f*>(s1 + bi * FILT + kq);
  const float* s2base = s2 + ((size_t)(b << 7) + jh * 64) * FILT;
  const float* dbase = dist + ((size_t)bi * NATOM + jh * 64) * 3;
  float* obase = out + ((size_t)bi * NATOM + jh * 64) * 3 * FILT;

#pragma unroll
  for (int s = 0; s < 8; ++s) {
    const int j0 = (w * 8 + s) * 2;  // wave's pair: j0, j0+1
    const int j1 = j0 + 1;
    const v4f p0 = s1v + *reinterpret_cast<const v4f*>(s2base + j0 * FILT + kq);
    const v4f p1 = s1v + *reinterpret_cast<const v4f*>(s2base + j1 * FILT + kq);
    const float d00 = dbase[j0 * 3 + 0], d01 = dbase[j0 * 3 + 1],
                d02 = dbase[j0 * 3 + 2];
    const float d10 = dbase[j1 * 3 + 0], d11 = dbase[j1 * 3 + 1],
                d12 = dbase[j1 * 3 + 2];

    // Flat float4 map over the pair's 768 floats: idx4 = t*64 + lane.
    // t=0: (j0,c0|c1)  t=1: (j0,c2 | j1,c0)  t=2: (j1,c1|c2)
    const v4f v0 = p0 * (hl ? d01 : d00);
    const v4f ps = hl ? p1 : p0;
    const v4f v1 = ps * (hl ? d10 : d02);
    const v4f v2 = p1 * (hl ? d12 : d11);

    float* oo = obase + (size_t)j0 * 3 * FILT + (size_t)lane * 4;
    *reinterpret_cast<v4f*>(oo) = v0;         // bytes [0,1024)
    *reinterpret_cast<v4f*>(oo + 256) = v1;   // bytes [1024,2048)
    *reinterpret_cast<v4f*>(oo + 512) = v2;   // bytes [2048,3072)
  }
}

extern "C" void kernel_launch(void* const* d_in, const int* in_sizes, int n_in,
                              void* d_out, int out_size, void* d_ws, size_t ws_size,
                              hipStream_t stream) {
  const float* sf   = (const float*)d_in[0];  // (8,128,128)
  const float* dist = (const float*)d_in[1];  // (8,128,128,3)
  const float* W    = (const float*)d_in[2];  // (256,128)
  const float* bias = (const float*)d_in[3];  // (1,128)
  float* out = (float*)d_out;                 // (8,128,128,3,128)

  float* s1 = (float*)d_ws;  // 1024*128 f32
  float* s2 = s1 + BATCH * NATOM * FILT;

  s_gemm_kernel<<<BATCH * NATOM / 2, 256, 0, stream>>>(sf, W, bias, s1, s2);
  expand_kernel<<<BATCH * NATOM * 2, 256, 0, stream>>>(s1, s2, dist, out);
}

// Round 9
// 41.245 us; speedup vs baseline: 1.0046x; 1.0046x over previous
//
#include <hip/hip_runtime.h>

typedef float v4f __attribute__((ext_vector_type(4)));

#define NATOM 128
#define FEAT 128
#define FILT 128
#define BATCH 8

// Kernel 1 (unchanged from R7): s-GEMM, 2 rows per block, 512 blocks.
__global__ __launch_bounds__(256) void s_gemm_kernel(
    const float* __restrict__ sf, const float* __restrict__ W,
    const float* __restrict__ bias, float* __restrict__ s1,
    float* __restrict__ s2) {
  const int r0 = blockIdx.x * 2;
  const int tid = threadIdx.x;
  const int k = tid & (FILT - 1);
  const int which = tid >> 7;  // 0 -> s1, 1 -> s2

  __shared__ float sfrow[2][FEAT];
  sfrow[tid >> 7][tid & 127] = sf[(r0 + (tid >> 7)) * FEAT + (tid & 127)];
  __syncthreads();

  const float* Wcol = W + which * FEAT * FILT + k;
  float a0 = 0.f, a1 = 0.f;
#pragma unroll 4
  for (int f4 = 0; f4 < FEAT; f4 += 4) {
    const v4f sv0 = *reinterpret_cast<const v4f*>(&sfrow[0][f4]);
    const v4f sv1 = *reinterpret_cast<const v4f*>(&sfrow[1][f4]);
#pragma unroll
    for (int fi = 0; fi < 4; ++fi) {
      const float w = Wcol[(f4 + fi) * FILT];
      a0 = fmaf(sv0[fi], w, a0);
      a1 = fmaf(sv1[fi], w, a1);
    }
  }

  const float bb = which ? 0.f : bias[k];
  float* dst = (which ? s2 : s1) + r0 * FILT + k;
  dst[0] = a0 + bb;
  dst[FILT] = a1 + bb;
}

// Kernel 2: out[b,i,j,c,k] = (s1[b,i,k] + s2[b,j,k]) * dist[b,i,j,c]
// R7 mapping (2048 blocks, 8 j-lanes x 32 k-quads). R8->R9 change: explicit
// two-phase schedule per wave. Phase 1: preload ALL reads (8x s2 v4f + 24
// dist scalars) into registers. sched_barrier(0) pins the boundary. Phase 2:
// 24 back-to-back stores, no intervening s_waitcnt. Rationale: vmcnt
// decrements IN ISSUE ORDER, so interleaved load->wait->store loops stall
// each iteration's load-wait behind the previous iteration's store-acks
// under write backpressure; splitting phases gives the fill kernel's
// wait-free store stream.
__global__ __launch_bounds__(256) void expand_kernel(
    const float* __restrict__ s1, const float* __restrict__ s2,
    const float* __restrict__ dist, float* __restrict__ out) {
  const int blk = blockIdx.x;
  const int bi = blk >> 1;         // b*N + i
  const int jh = blk & 1;          // which half of j
  const int b = bi >> 7;
  const int tid = threadIdx.x;
  const int kq = (tid & 31) << 2;  // k offset: 0..124 step 4
  const int jl = tid >> 5;         // 0..7

  const v4f s1v = *reinterpret_cast<const v4f*>(s1 + bi * FILT + kq);
  const float* s2base = s2 + ((size_t)(b << 7) + jh * 64) * FILT;
  const float* dbase = dist + ((size_t)bi * NATOM + jh * 64) * 3;
  float* obase = out + ((size_t)bi * NATOM + jh * 64) * 3 * FILT;

  // ---- Phase 1: preload everything (all indices compile-time after unroll)
  v4f s2v[8];
  float dd[8][3];
#pragma unroll
  for (int s = 0; s < 8; ++s) {
    const int jloc = s * 8 + jl;
    s2v[s] = *reinterpret_cast<const v4f*>(s2base + jloc * FILT + kq);
    dd[s][0] = dbase[jloc * 3 + 0];
    dd[s][1] = dbase[jloc * 3 + 1];
    dd[s][2] = dbase[jloc * 3 + 2];
  }

  __builtin_amdgcn_sched_barrier(0);  // no store hoisted above this line

  // ---- Phase 2: pure store stream
#pragma unroll
  for (int s = 0; s < 8; ++s) {
    const int jloc = s * 8 + jl;
    const v4f p = s1v + s2v[s];
    float* o = obase + (size_t)jloc * 3 * FILT + kq;
    *reinterpret_cast<v4f*>(o) = p * dd[s][0];
    *reinterpret_cast<v4f*>(o + FILT) = p * dd[s][1];
    *reinterpret_cast<v4f*>(o + 2 * FILT) = p * dd[s][2];
  }
}

extern "C" void kernel_launch(void* const* d_in, const int* in_sizes, int n_in,
                              void* d_out, int out_size, void* d_ws, size_t ws_size,
                              hipStream_t stream) {
  const float* sf   = (const float*)d_in[0];  // (8,128,128)
  const float* dist = (const float*)d_in[1];  // (8,128,128,3)
  const float* W    = (const float*)d_in[2];  // (256,128)
  const float* bias = (const float*)d_in[3];  // (1,128)
  float* out = (float*)d_out;                 // (8,128,128,3,128)

  float* s1 = (float*)d_ws;  // 1024*128 f32
  float* s2 = s1 + BATCH * NATOM * FILT;

  s_gemm_kernel<<<BATCH * NATOM / 2, 256, 0, stream>>>(sf, W, bias, s1, s2);
  expand_kernel<<<BATCH * NATOM * 2, 256, 0, stream>>>(s1, s2, dist, out);
}